// Round 3
// baseline (774.251 us; speedup 1.0000x reference)
//
#include <hip/hip_runtime.h>

#define NN 100000
#define NE 1600000

static __device__ __forceinline__ unsigned f2bf(float f) {
    unsigned u = __float_as_uint(f);
    return (u + 0x7fffu + ((u >> 16) & 1u)) >> 16;   // RNE
}

// ---------------------------------------------------------------------------
// k1: h = X @ W  (fp32 compute, W in LDS, 4 rows x 32 cols per thread)
//     writes h as bf16 [NN][128]; fused per-node attention partial dots:
//       asrc[n,h] = dot(h[n,h,:], a[h,0:32]),  adst[n,h] = dot(h[n,h,:], a[h,32:64])
// ---------------------------------------------------------------------------
__global__ __launch_bounds__(256) void k1_gemm_alpha(
    const float* __restrict__ X, const float* __restrict__ W,
    const float* __restrict__ a, unsigned short* __restrict__ h16,
    float* __restrict__ asrc, float* __restrict__ adst)
{
    __shared__ float sW[128 * 128];  // 64 KB, swizzled
    {
        const float4* W4 = (const float4*)W;
        float4* sW4 = (float4*)sW;
        #pragma unroll
        for (int i = 0; i < 16; ++i) {
            int idx = threadIdx.x + i * 256;   // 0..4095 float4 granules
            int cg  = idx & 31;                // col granule within k-row
            int k   = idx >> 5;
            int cgs = cg ^ ((cg >> 3) & 3);    // bank swizzle (per col-quarter)
            sW4[(k << 5) + cgs] = W4[idx];
        }
    }
    __syncthreads();

    const int q  = threadIdx.x & 3;   // head / col-quarter (cols q*32..q*32+31)
    const int rg = threadIdx.x >> 2;  // 0..63
    const int row0 = blockIdx.x * 256;

    int rows[4];
    const float4* x4[4];
    #pragma unroll
    for (int i = 0; i < 4; ++i) {
        int r = row0 + rg + i * 64;
        rows[i] = r;
        int rc = r < NN ? r : (NN - 1);
        x4[i] = (const float4*)(X + (size_t)rc * 128);
    }

    float acc[4][32];
    #pragma unroll
    for (int i = 0; i < 4; ++i) {
        #pragma unroll
        for (int c = 0; c < 32; ++c) acc[i][c] = 0.f;
    }

    const float4* sW4r = (const float4*)sW;
    for (int k4 = 0; k4 < 32; ++k4) {
        float xs[4][4];
        #pragma unroll
        for (int i = 0; i < 4; ++i) {
            float4 xv = x4[i][k4];
            xs[i][0] = xv.x; xs[i][1] = xv.y; xs[i][2] = xv.z; xs[i][3] = xv.w;
        }
        #pragma unroll
        for (int j = 0; j < 4; ++j) {
            const int k = (k4 << 2) + j;
            const float4* wr = sW4r + (k << 5) + (q << 3);
            #pragma unroll
            for (int c = 0; c < 8; ++c) {
                float4 wv = wr[c ^ q];  // un-swizzle: logical granule c
                #pragma unroll
                for (int i = 0; i < 4; ++i) {
                    acc[i][(c << 2) + 0] = fmaf(xs[i][j], wv.x, acc[i][(c << 2) + 0]);
                    acc[i][(c << 2) + 1] = fmaf(xs[i][j], wv.y, acc[i][(c << 2) + 1]);
                    acc[i][(c << 2) + 2] = fmaf(xs[i][j], wv.z, acc[i][(c << 2) + 2]);
                    acc[i][(c << 2) + 3] = fmaf(xs[i][j], wv.w, acc[i][(c << 2) + 3]);
                }
            }
        }
    }

    // stage 'a' (256 floats) into LDS (reuse sW; all k-loop reads are done)
    __syncthreads();
    sW[threadIdx.x] = a[threadIdx.x];
    __syncthreads();
    const float* av = sW + q * 64;

    #pragma unroll
    for (int i = 0; i < 4; ++i) {
        if (rows[i] >= NN) continue;
        float ssrc = 0.f, sdst = 0.f;
        #pragma unroll
        for (int c = 0; c < 32; ++c) {
            ssrc = fmaf(acc[i][c], av[c], ssrc);
            sdst = fmaf(acc[i][c], av[32 + c], sdst);
        }
        // pack 32 accs -> 16 uints (bf16x2) -> 4 uint4 stores
        unsigned short* hr = h16 + (size_t)rows[i] * 128 + q * 32;
        uint4* hr4 = (uint4*)hr;
        #pragma unroll
        for (int g = 0; g < 4; ++g) {
            uint4 pk;
            pk.x = f2bf(acc[i][g * 8 + 0]) | (f2bf(acc[i][g * 8 + 1]) << 16);
            pk.y = f2bf(acc[i][g * 8 + 2]) | (f2bf(acc[i][g * 8 + 3]) << 16);
            pk.z = f2bf(acc[i][g * 8 + 4]) | (f2bf(acc[i][g * 8 + 5]) << 16);
            pk.w = f2bf(acc[i][g * 8 + 6]) | (f2bf(acc[i][g * 8 + 7]) << 16);
            hr4[g] = pk;
        }
        asrc[rows[i] * 4 + q] = ssrc;
        adst[rows[i] * 4 + q] = sdst;
    }
}

// ---------------------------------------------------------------------------
// kc: in-degree histogram
// ---------------------------------------------------------------------------
__global__ __launch_bounds__(256) void kc_count(
    const int* __restrict__ ei, int* __restrict__ counts)
{
    int e = blockIdx.x * 256 + threadIdx.x;
    if (e >= NE) return;
    atomicAdd(counts + ei[NE + e], 1);
}

// ---------------------------------------------------------------------------
// kscan: single-block exclusive scan of counts[NN] -> cursor[NN] (row starts)
// ---------------------------------------------------------------------------
#define SCAN_T 1024
#define CHUNK 98   // ceil(100000/1024)
__global__ __launch_bounds__(SCAN_T) void kscan(
    const int* __restrict__ counts, int* __restrict__ cursor)
{
    __shared__ int part[SCAN_T];
    int t = threadIdx.x;
    int beg = t * CHUNK;
    int end = beg + CHUNK; if (end > NN) end = NN;
    int s = 0;
    for (int i = beg; i < end; ++i) s += counts[i];
    part[t] = s;
    __syncthreads();
    for (int off = 1; off < SCAN_T; off <<= 1) {
        int v = (t >= off) ? part[t - off] : 0;
        __syncthreads();
        part[t] += v;
        __syncthreads();
    }
    int run = (t == 0) ? 0 : part[t - 1];
    for (int i = beg; i < end; ++i) { cursor[i] = run; run += counts[i]; }
}

// ---------------------------------------------------------------------------
// k3: scatter edges into CSR slots (csr_src only) + atomic per-dst exp sums.
//     after this kernel: cursor[n] = row_end(n); row_start(n) = cursor[n]-counts[n]
// ---------------------------------------------------------------------------
__global__ __launch_bounds__(256) void k3_scatter(
    const int* __restrict__ ei, const float* __restrict__ asrc,
    const float* __restrict__ adst, int* __restrict__ cursor,
    int* __restrict__ csr_src, float* __restrict__ sum_exp)
{
    int e = blockIdx.x * 256 + threadIdx.x;
    if (e >= NE) return;
    int src = ei[e];
    int dst = ei[NE + e];
    float4 s4 = *(const float4*)(asrc + (size_t)src * 4);
    float4 d4 = *(const float4*)(adst + (size_t)dst * 4);
    float sc0 = s4.x + d4.x;
    float sc1 = s4.y + d4.y;
    float sc2 = s4.z + d4.z;
    float sc3 = s4.w + d4.w;
    sc0 = sc0 >= 0.f ? sc0 : 0.2f * sc0;
    sc1 = sc1 >= 0.f ? sc1 : 0.2f * sc1;
    sc2 = sc2 >= 0.f ? sc2 : 0.2f * sc2;
    sc3 = sc3 >= 0.f ? sc3 : 0.2f * sc3;
    int p = atomicAdd(cursor + dst, 1);
    csr_src[p] = src;
    float* sb = sum_exp + (size_t)dst * 4;
    unsafeAtomicAdd(sb + 0, __expf(sc0));
    unsafeAtomicAdd(sb + 1, __expf(sc1));
    unsafeAtomicAdd(sb + 2, __expf(sc2));
    unsafeAtomicAdd(sb + 3, __expf(sc3));
}

// ---------------------------------------------------------------------------
// k4: one wave per dst node; four 16-lane groups each process every 4th edge.
//     Recompute attn weight from L2-resident alpha tables; gather h[src]
//     (bf16, 16 lanes x 16B = full 256B row per group); register accumulate;
//     cross-group shfl reduce; one coalesced 512B write per node.
// ---------------------------------------------------------------------------
__global__ __launch_bounds__(256) void k4_agg(
    const int* __restrict__ counts, const int* __restrict__ cursor,
    const int* __restrict__ csr_src, const float* __restrict__ asrc,
    const float* __restrict__ adst, const float* __restrict__ sum_exp,
    const unsigned short* __restrict__ h16, float* __restrict__ out)
{
    int wid = (blockIdx.x * 256 + threadIdx.x) >> 6;
    if (wid >= NN) return;
    int l = threadIdx.x & 63;
    int g = l >> 4;           // edge subgroup 0..3
    int cidx = l & 15;        // col granule: cols cidx*8 .. cidx*8+7
    int head = cidx >> 2;

    int end = cursor[wid];
    int beg = end - counts[wid];

    float ad = adst[(size_t)wid * 4 + head];
    float rs = 1.0f / (sum_exp[(size_t)wid * 4 + head] + 1e-16f);

    float acc[8];
    #pragma unroll
    for (int c = 0; c < 8; ++c) acc[c] = 0.f;

    for (int i = beg + g; i < end; i += 4) {
        int src = csr_src[i];
        float sc = asrc[(size_t)src * 4 + head] + ad;
        sc = sc >= 0.f ? sc : 0.2f * sc;
        float w = __expf(sc) * rs;
        uint4 hv = *(const uint4*)(h16 + (size_t)src * 128 + cidx * 8);
        acc[0] = fmaf(w, __uint_as_float(hv.x << 16),       acc[0]);
        acc[1] = fmaf(w, __uint_as_float(hv.x & 0xffff0000u), acc[1]);
        acc[2] = fmaf(w, __uint_as_float(hv.y << 16),       acc[2]);
        acc[3] = fmaf(w, __uint_as_float(hv.y & 0xffff0000u), acc[3]);
        acc[4] = fmaf(w, __uint_as_float(hv.z << 16),       acc[4]);
        acc[5] = fmaf(w, __uint_as_float(hv.z & 0xffff0000u), acc[5]);
        acc[6] = fmaf(w, __uint_as_float(hv.w << 16),       acc[6]);
        acc[7] = fmaf(w, __uint_as_float(hv.w & 0xffff0000u), acc[7]);
    }

    // reduce across the 4 groups (lanes sharing cidx)
    #pragma unroll
    for (int c = 0; c < 8; ++c) {
        acc[c] += __shfl_xor(acc[c], 16);
        acc[c] += __shfl_xor(acc[c], 32);
    }
    if (g == 0) {
        float4* ob = (float4*)(out + (size_t)wid * 128 + cidx * 8);
        ob[0] = make_float4(acc[0], acc[1], acc[2], acc[3]);
        ob[1] = make_float4(acc[4], acc[5], acc[6], acc[7]);
    }
}

// ---------------------------------------------------------------------------
extern "C" void kernel_launch(void* const* d_in, const int* in_sizes, int n_in,
                              void* d_out, int out_size, void* d_ws, size_t ws_size,
                              hipStream_t stream)
{
    const float* X  = (const float*)d_in[0];
    const int*   ei = (const int*)d_in[1];
    const float* W  = (const float*)d_in[2];
    const float* a  = (const float*)d_in[3];
    float* out = (float*)d_out;

    // workspace layout (4-byte elements), total ~37.6 MB
    unsigned short* h16 = (unsigned short*)d_ws;          // NN*128 bf16 = 6.4M elems
    float* asrc    = (float*)d_ws + 6400000;              // NN*4
    float* adst    = asrc + 400000;                       // NN*4
    float* sum_exp = adst + 400000;                       // NN*4
    int*   counts  = (int*)(sum_exp + 400000);            // NN
    int*   cursor  = counts + 100000;                     // NN
    int*   csr_src = cursor + 100000;                     // NE

    // zero sum_exp + counts in one shot (adjacent)
    hipMemsetAsync(sum_exp, 0, (400000 + 100000) * sizeof(int), stream);

    k1_gemm_alpha<<<(NN + 255) / 256, 256, 0, stream>>>(X, W, a, h16, asrc, adst);
    kc_count<<<(NE + 255) / 256, 256, 0, stream>>>(ei, counts);
    kscan<<<1, SCAN_T, 0, stream>>>(counts, cursor);
    k3_scatter<<<(NE + 255) / 256, 256, 0, stream>>>(ei, asrc, adst, cursor,
                                                     csr_src, sum_exp);
    k4_agg<<<(NN * 64 + 255) / 256, 256, 0, stream>>>(counts, cursor, csr_src,
                                                      asrc, adst, sum_exp, h16, out);
}

// Round 4
// 514.251 us; speedup vs baseline: 1.5056x; 1.5056x over previous
//
#include <hip/hip_runtime.h>

#define NN 100000
#define NE 1600000

static __device__ __forceinline__ unsigned f2bf(float f) {
    unsigned u = __float_as_uint(f);
    return (u + 0x7fffu + ((u >> 16) & 1u)) >> 16;   // RNE
}

// ---------------------------------------------------------------------------
// k1: h = X @ W  (fp32 compute, W in LDS, 4 rows x 32 cols per thread)
//     writes h as bf16 [NN][128]; fused per-node attention partial dots:
//       asrc[n,h] = dot(h[n,h,:], a[h,0:32]),  adst[n,h] = dot(h[n,h,:], a[h,32:64])
// ---------------------------------------------------------------------------
__global__ __launch_bounds__(256) void k1_gemm_alpha(
    const float* __restrict__ X, const float* __restrict__ W,
    const float* __restrict__ a, unsigned short* __restrict__ h16,
    float* __restrict__ asrc, float* __restrict__ adst)
{
    __shared__ float sW[128 * 128];  // 64 KB, swizzled
    {
        const float4* W4 = (const float4*)W;
        float4* sW4 = (float4*)sW;
        #pragma unroll
        for (int i = 0; i < 16; ++i) {
            int idx = threadIdx.x + i * 256;   // 0..4095 float4 granules
            int cg  = idx & 31;                // col granule within k-row
            int k   = idx >> 5;
            int cgs = cg ^ ((cg >> 3) & 3);    // bank swizzle (per col-quarter)
            sW4[(k << 5) + cgs] = W4[idx];
        }
    }
    __syncthreads();

    const int q  = threadIdx.x & 3;   // head / col-quarter (cols q*32..q*32+31)
    const int rg = threadIdx.x >> 2;  // 0..63
    const int row0 = blockIdx.x * 256;

    int rows[4];
    const float4* x4[4];
    #pragma unroll
    for (int i = 0; i < 4; ++i) {
        int r = row0 + rg + i * 64;
        rows[i] = r;
        int rc = r < NN ? r : (NN - 1);
        x4[i] = (const float4*)(X + (size_t)rc * 128);
    }

    float acc[4][32];
    #pragma unroll
    for (int i = 0; i < 4; ++i) {
        #pragma unroll
        for (int c = 0; c < 32; ++c) acc[i][c] = 0.f;
    }

    const float4* sW4r = (const float4*)sW;
    for (int k4 = 0; k4 < 32; ++k4) {
        float xs[4][4];
        #pragma unroll
        for (int i = 0; i < 4; ++i) {
            float4 xv = x4[i][k4];
            xs[i][0] = xv.x; xs[i][1] = xv.y; xs[i][2] = xv.z; xs[i][3] = xv.w;
        }
        #pragma unroll
        for (int j = 0; j < 4; ++j) {
            const int k = (k4 << 2) + j;
            const float4* wr = sW4r + (k << 5) + (q << 3);
            #pragma unroll
            for (int c = 0; c < 8; ++c) {
                float4 wv = wr[c ^ q];  // un-swizzle: logical granule c
                #pragma unroll
                for (int i = 0; i < 4; ++i) {
                    acc[i][(c << 2) + 0] = fmaf(xs[i][j], wv.x, acc[i][(c << 2) + 0]);
                    acc[i][(c << 2) + 1] = fmaf(xs[i][j], wv.y, acc[i][(c << 2) + 1]);
                    acc[i][(c << 2) + 2] = fmaf(xs[i][j], wv.z, acc[i][(c << 2) + 2]);
                    acc[i][(c << 2) + 3] = fmaf(xs[i][j], wv.w, acc[i][(c << 2) + 3]);
                }
            }
        }
    }

    // stage 'a' (256 floats) into LDS (reuse sW; all k-loop reads are done)
    __syncthreads();
    sW[threadIdx.x] = a[threadIdx.x];
    __syncthreads();
    const float* av = sW + q * 64;

    #pragma unroll
    for (int i = 0; i < 4; ++i) {
        if (rows[i] >= NN) continue;
        float ssrc = 0.f, sdst = 0.f;
        #pragma unroll
        for (int c = 0; c < 32; ++c) {
            ssrc = fmaf(acc[i][c], av[c], ssrc);
            sdst = fmaf(acc[i][c], av[32 + c], sdst);
        }
        // pack 32 accs -> 16 uints (bf16x2) -> 4 uint4 stores
        unsigned short* hr = h16 + (size_t)rows[i] * 128 + q * 32;
        uint4* hr4 = (uint4*)hr;
        #pragma unroll
        for (int g = 0; g < 4; ++g) {
            uint4 pk;
            pk.x = f2bf(acc[i][g * 8 + 0]) | (f2bf(acc[i][g * 8 + 1]) << 16);
            pk.y = f2bf(acc[i][g * 8 + 2]) | (f2bf(acc[i][g * 8 + 3]) << 16);
            pk.z = f2bf(acc[i][g * 8 + 4]) | (f2bf(acc[i][g * 8 + 5]) << 16);
            pk.w = f2bf(acc[i][g * 8 + 6]) | (f2bf(acc[i][g * 8 + 7]) << 16);
            hr4[g] = pk;
        }
        asrc[rows[i] * 4 + q] = ssrc;
        adst[rows[i] * 4 + q] = sdst;
    }
}

// ---------------------------------------------------------------------------
// kc: in-degree histogram
// ---------------------------------------------------------------------------
__global__ __launch_bounds__(256) void kc_count(
    const int* __restrict__ ei, int* __restrict__ counts)
{
    int e = blockIdx.x * 256 + threadIdx.x;
    if (e >= NE) return;
    atomicAdd(counts + ei[NE + e], 1);
}

// ---------------------------------------------------------------------------
// kscan: single-block exclusive scan of counts[NN] -> cursor[NN] (row starts)
// ---------------------------------------------------------------------------
#define SCAN_T 1024
#define CHUNK 98   // ceil(100000/1024)
__global__ __launch_bounds__(SCAN_T) void kscan(
    const int* __restrict__ counts, int* __restrict__ cursor)
{
    __shared__ int part[SCAN_T];
    int t = threadIdx.x;
    int beg = t * CHUNK;
    int end = beg + CHUNK; if (end > NN) end = NN;
    int s = 0;
    for (int i = beg; i < end; ++i) s += counts[i];
    part[t] = s;
    __syncthreads();
    for (int off = 1; off < SCAN_T; off <<= 1) {
        int v = (t >= off) ? part[t - off] : 0;
        __syncthreads();
        part[t] += v;
        __syncthreads();
    }
    int run = (t == 0) ? 0 : part[t - 1];
    for (int i = beg; i < end; ++i) { cursor[i] = run; run += counts[i]; }
}

// ---------------------------------------------------------------------------
// k3: pure CSR scatter (no score math, no float atomics).
//     after this kernel: cursor[n] = row_end(n); row_start(n) = cursor[n]-counts[n]
// ---------------------------------------------------------------------------
__global__ __launch_bounds__(256) void k3_scatter(
    const int* __restrict__ ei, int* __restrict__ cursor,
    int* __restrict__ csr_src)
{
    int e = blockIdx.x * 256 + threadIdx.x;
    if (e >= NE) return;
    int src = ei[e];
    int dst = ei[NE + e];
    int p = atomicAdd(cursor + dst, 1);
    csr_src[p] = src;
}

// ---------------------------------------------------------------------------
// k4: one wave per dst node; four 16-lane groups each process every 4th edge.
//     Single pass: accumulate unnormalized sum_c(exp*h) AND scalar sum(exp);
//     normalize once at the end:  out = acc / (sum + eps).
//     h gather: 16 lanes x 16B = full 256B bf16 row per group.
// ---------------------------------------------------------------------------
__global__ __launch_bounds__(256) void k4_agg(
    const int* __restrict__ counts, const int* __restrict__ cursor,
    const int* __restrict__ csr_src, const float* __restrict__ asrc,
    const float* __restrict__ adst,
    const unsigned short* __restrict__ h16, float* __restrict__ out)
{
    int wid = (blockIdx.x * 256 + threadIdx.x) >> 6;
    if (wid >= NN) return;
    int l = threadIdx.x & 63;
    int g = l >> 4;           // edge subgroup 0..3
    int cidx = l & 15;        // col granule: cols cidx*8 .. cidx*8+7
    int head = cidx >> 2;

    int end = cursor[wid];
    int beg = end - counts[wid];

    float ad = adst[(size_t)wid * 4 + head];

    float acc[8];
    #pragma unroll
    for (int c = 0; c < 8; ++c) acc[c] = 0.f;
    float sum = 0.f;

    for (int i = beg + g; i < end; i += 4) {
        int src = csr_src[i];
        float sc = asrc[(size_t)src * 4 + head] + ad;
        sc = sc >= 0.f ? sc : 0.2f * sc;
        float w = __expf(sc);
        sum += w;
        uint4 hv = *(const uint4*)(h16 + (size_t)src * 128 + cidx * 8);
        acc[0] = fmaf(w, __uint_as_float(hv.x << 16),         acc[0]);
        acc[1] = fmaf(w, __uint_as_float(hv.x & 0xffff0000u), acc[1]);
        acc[2] = fmaf(w, __uint_as_float(hv.y << 16),         acc[2]);
        acc[3] = fmaf(w, __uint_as_float(hv.y & 0xffff0000u), acc[3]);
        acc[4] = fmaf(w, __uint_as_float(hv.z << 16),         acc[4]);
        acc[5] = fmaf(w, __uint_as_float(hv.z & 0xffff0000u), acc[5]);
        acc[6] = fmaf(w, __uint_as_float(hv.w << 16),         acc[6]);
        acc[7] = fmaf(w, __uint_as_float(hv.w & 0xffff0000u), acc[7]);
    }

    // reduce acc and sum across the 4 groups (lanes sharing cidx)
    #pragma unroll
    for (int c = 0; c < 8; ++c) {
        acc[c] += __shfl_xor(acc[c], 16);
        acc[c] += __shfl_xor(acc[c], 32);
    }
    sum += __shfl_xor(sum, 16);
    sum += __shfl_xor(sum, 32);

    if (g == 0) {
        float rs = 1.0f / (sum + 1e-16f);
        float4* ob = (float4*)(out + (size_t)wid * 128 + cidx * 8);
        ob[0] = make_float4(acc[0] * rs, acc[1] * rs, acc[2] * rs, acc[3] * rs);
        ob[1] = make_float4(acc[4] * rs, acc[5] * rs, acc[6] * rs, acc[7] * rs);
    }
}

// ---------------------------------------------------------------------------
extern "C" void kernel_launch(void* const* d_in, const int* in_sizes, int n_in,
                              void* d_out, int out_size, void* d_ws, size_t ws_size,
                              hipStream_t stream)
{
    const float* X  = (const float*)d_in[0];
    const int*   ei = (const int*)d_in[1];
    const float* W  = (const float*)d_in[2];
    const float* a  = (const float*)d_in[3];
    float* out = (float*)d_out;

    // workspace layout (4-byte elements), total ~34.4 MB
    unsigned short* h16 = (unsigned short*)d_ws;          // NN*128 bf16 = 6.4M elems
    float* asrc    = (float*)d_ws + 6400000;              // NN*4
    float* adst    = asrc + 400000;                       // NN*4
    int*   counts  = (int*)(adst + 400000);               // NN
    int*   cursor  = counts + 100000;                     // NN
    int*   csr_src = cursor + 100000;                     // NE

    hipMemsetAsync(counts, 0, NN * sizeof(int), stream);

    k1_gemm_alpha<<<(NN + 255) / 256, 256, 0, stream>>>(X, W, a, h16, asrc, adst);
    kc_count<<<(NE + 255) / 256, 256, 0, stream>>>(ei, counts);
    kscan<<<1, SCAN_T, 0, stream>>>(counts, cursor);
    k3_scatter<<<(NE + 255) / 256, 256, 0, stream>>>(ei, cursor, csr_src);
    k4_agg<<<(NN * 64 + 255) / 256, 256, 0, stream>>>(counts, cursor, csr_src,
                                                      asrc, adst, h16, out);
}

// Round 5
// 365.001 us; speedup vs baseline: 2.1212x; 1.4089x over previous
//
#include <hip/hip_runtime.h>

#define NN 100000
#define NE 1600000
#define SCAN_BLK 98   // ceil(100000/1024)

static __device__ __forceinline__ unsigned f2bf(float f) {
    unsigned u = __float_as_uint(f);
    return (u + 0x7fffu + ((u >> 16) & 1u)) >> 16;   // RNE
}

// ---------------------------------------------------------------------------
// k1: h = X @ W  (fp32 compute, W in LDS, 4 rows x 32 cols per thread)
//     writes h as bf16 [NN][128]; fused per-node attention partial dots:
//       asrc[n,h] = dot(h[n,h,:], a[h,0:32]),  adst[n,h] = dot(h[n,h,:], a[h,32:64])
// ---------------------------------------------------------------------------
__global__ __launch_bounds__(256) void k1_gemm_alpha(
    const float* __restrict__ X, const float* __restrict__ W,
    const float* __restrict__ a, unsigned short* __restrict__ h16,
    float* __restrict__ asrc, float* __restrict__ adst)
{
    __shared__ float sW[128 * 128];  // 64 KB, swizzled
    {
        const float4* W4 = (const float4*)W;
        float4* sW4 = (float4*)sW;
        #pragma unroll
        for (int i = 0; i < 16; ++i) {
            int idx = threadIdx.x + i * 256;   // 0..4095 float4 granules
            int cg  = idx & 31;                // col granule within k-row
            int k   = idx >> 5;
            int cgs = cg ^ ((cg >> 3) & 3);    // bank swizzle (per col-quarter)
            sW4[(k << 5) + cgs] = W4[idx];
        }
    }
    __syncthreads();

    const int q  = threadIdx.x & 3;   // head / col-quarter (cols q*32..q*32+31)
    const int rg = threadIdx.x >> 2;  // 0..63
    const int row0 = blockIdx.x * 256;

    int rows[4];
    const float4* x4[4];
    #pragma unroll
    for (int i = 0; i < 4; ++i) {
        int r = row0 + rg + i * 64;
        rows[i] = r;
        int rc = r < NN ? r : (NN - 1);
        x4[i] = (const float4*)(X + (size_t)rc * 128);
    }

    float acc[4][32];
    #pragma unroll
    for (int i = 0; i < 4; ++i) {
        #pragma unroll
        for (int c = 0; c < 32; ++c) acc[i][c] = 0.f;
    }

    const float4* sW4r = (const float4*)sW;
    for (int k4 = 0; k4 < 32; ++k4) {
        float xs[4][4];
        #pragma unroll
        for (int i = 0; i < 4; ++i) {
            float4 xv = x4[i][k4];
            xs[i][0] = xv.x; xs[i][1] = xv.y; xs[i][2] = xv.z; xs[i][3] = xv.w;
        }
        #pragma unroll
        for (int j = 0; j < 4; ++j) {
            const int k = (k4 << 2) + j;
            const float4* wr = sW4r + (k << 5) + (q << 3);
            #pragma unroll
            for (int c = 0; c < 8; ++c) {
                float4 wv = wr[c ^ q];  // un-swizzle: logical granule c
                #pragma unroll
                for (int i = 0; i < 4; ++i) {
                    acc[i][(c << 2) + 0] = fmaf(xs[i][j], wv.x, acc[i][(c << 2) + 0]);
                    acc[i][(c << 2) + 1] = fmaf(xs[i][j], wv.y, acc[i][(c << 2) + 1]);
                    acc[i][(c << 2) + 2] = fmaf(xs[i][j], wv.z, acc[i][(c << 2) + 2]);
                    acc[i][(c << 2) + 3] = fmaf(xs[i][j], wv.w, acc[i][(c << 2) + 3]);
                }
            }
        }
    }

    // stage 'a' (256 floats) into LDS (reuse sW; all k-loop reads are done)
    __syncthreads();
    sW[threadIdx.x] = a[threadIdx.x];
    __syncthreads();
    const float* av = sW + q * 64;

    #pragma unroll
    for (int i = 0; i < 4; ++i) {
        if (rows[i] >= NN) continue;
        float ssrc = 0.f, sdst = 0.f;
        #pragma unroll
        for (int c = 0; c < 32; ++c) {
            ssrc = fmaf(acc[i][c], av[c], ssrc);
            sdst = fmaf(acc[i][c], av[32 + c], sdst);
        }
        // pack 32 accs -> 16 uints (bf16x2) -> 4 uint4 stores
        unsigned short* hr = h16 + (size_t)rows[i] * 128 + q * 32;
        uint4* hr4 = (uint4*)hr;
        #pragma unroll
        for (int g = 0; g < 4; ++g) {
            uint4 pk;
            pk.x = f2bf(acc[i][g * 8 + 0]) | (f2bf(acc[i][g * 8 + 1]) << 16);
            pk.y = f2bf(acc[i][g * 8 + 2]) | (f2bf(acc[i][g * 8 + 3]) << 16);
            pk.z = f2bf(acc[i][g * 8 + 4]) | (f2bf(acc[i][g * 8 + 5]) << 16);
            pk.w = f2bf(acc[i][g * 8 + 6]) | (f2bf(acc[i][g * 8 + 7]) << 16);
            hr4[g] = pk;
        }
        asrc[rows[i] * 4 + q] = ssrc;
        adst[rows[i] * 4 + q] = sdst;
    }
}

// ---------------------------------------------------------------------------
// kc: in-degree histogram
// ---------------------------------------------------------------------------
__global__ __launch_bounds__(256) void kc_count(
    const int* __restrict__ ei, int* __restrict__ counts)
{
    int e = blockIdx.x * 256 + threadIdx.x;
    if (e >= NE) return;
    atomicAdd(counts + ei[NE + e], 1);
}

// ---------------------------------------------------------------------------
// hierarchical exclusive scan of counts[NN] -> cursor[NN]
// ---------------------------------------------------------------------------
__global__ __launch_bounds__(1024) void kscan1(
    const int* __restrict__ counts, int* __restrict__ bsum)
{
    int i = blockIdx.x * 1024 + threadIdx.x;
    int v = (i < NN) ? counts[i] : 0;
    __shared__ int red[16];
    #pragma unroll
    for (int off = 1; off < 64; off <<= 1) v += __shfl_xor(v, off);
    if ((threadIdx.x & 63) == 0) red[threadIdx.x >> 6] = v;
    __syncthreads();
    if (threadIdx.x < 16) {
        int s = red[threadIdx.x];
        #pragma unroll
        for (int off = 1; off < 16; off <<= 1) s += __shfl_xor(s, off);
        if (threadIdx.x == 0) bsum[blockIdx.x] = s;
    }
}

__global__ __launch_bounds__(128) void kscan2(
    const int* __restrict__ bsum, int* __restrict__ boff)
{
    __shared__ int sh[128];
    int t = threadIdx.x;
    sh[t] = (t < SCAN_BLK) ? bsum[t] : 0;
    __syncthreads();
    for (int off = 1; off < 128; off <<= 1) {
        int u = (t >= off) ? sh[t - off] : 0;
        __syncthreads();
        sh[t] += u;
        __syncthreads();
    }
    if (t < SCAN_BLK) boff[t] = (t == 0) ? 0 : sh[t - 1];
}

__global__ __launch_bounds__(1024) void kscan3(
    const int* __restrict__ counts, const int* __restrict__ boff,
    int* __restrict__ cursor)
{
    __shared__ int sh[1024];
    int i = blockIdx.x * 1024 + threadIdx.x;
    int t = threadIdx.x;
    int v = (i < NN) ? counts[i] : 0;
    sh[t] = v;
    __syncthreads();
    for (int off = 1; off < 1024; off <<= 1) {
        int u = (t >= off) ? sh[t - off] : 0;
        __syncthreads();
        sh[t] += u;
        __syncthreads();
    }
    if (i < NN) cursor[i] = boff[blockIdx.x] + sh[t] - v;  // exclusive
}

// ---------------------------------------------------------------------------
// k3: pure CSR scatter.
//     after this kernel: cursor[n] = row_end(n); row_start(n) = cursor[n]-counts[n]
// ---------------------------------------------------------------------------
__global__ __launch_bounds__(256) void k3_scatter(
    const int* __restrict__ ei, int* __restrict__ cursor,
    int* __restrict__ csr_src)
{
    int e = blockIdx.x * 256 + threadIdx.x;
    if (e >= NE) return;
    int src = ei[e];
    int dst = ei[NE + e];
    int p = atomicAdd(cursor + dst, 1);
    csr_src[p] = src;
}

// ---------------------------------------------------------------------------
// k4: one wave per dst node; four 16-lane groups each process every 4th edge.
//     Single pass: accumulate unnormalized sum_c(exp*h) AND scalar sum(exp);
//     normalize once at the end:  out = acc / (sum + eps).
// ---------------------------------------------------------------------------
__global__ __launch_bounds__(256) void k4_agg(
    const int* __restrict__ counts, const int* __restrict__ cursor,
    const int* __restrict__ csr_src, const float* __restrict__ asrc,
    const float* __restrict__ adst,
    const unsigned short* __restrict__ h16, float* __restrict__ out)
{
    int wid = (blockIdx.x * 256 + threadIdx.x) >> 6;
    if (wid >= NN) return;
    int l = threadIdx.x & 63;
    int g = l >> 4;           // edge subgroup 0..3
    int cidx = l & 15;        // col granule: cols cidx*8 .. cidx*8+7
    int head = cidx >> 2;

    int end = cursor[wid];
    int beg = end - counts[wid];

    float ad = adst[(size_t)wid * 4 + head];

    float acc[8];
    #pragma unroll
    for (int c = 0; c < 8; ++c) acc[c] = 0.f;
    float sum = 0.f;

    for (int i = beg + g; i < end; i += 4) {
        int src = csr_src[i];
        float sc = asrc[(size_t)src * 4 + head] + ad;
        sc = sc >= 0.f ? sc : 0.2f * sc;
        float w = __expf(sc);
        sum += w;
        uint4 hv = *(const uint4*)(h16 + (size_t)src * 128 + cidx * 8);
        acc[0] = fmaf(w, __uint_as_float(hv.x << 16),         acc[0]);
        acc[1] = fmaf(w, __uint_as_float(hv.x & 0xffff0000u), acc[1]);
        acc[2] = fmaf(w, __uint_as_float(hv.y << 16),         acc[2]);
        acc[3] = fmaf(w, __uint_as_float(hv.y & 0xffff0000u), acc[3]);
        acc[4] = fmaf(w, __uint_as_float(hv.z << 16),         acc[4]);
        acc[5] = fmaf(w, __uint_as_float(hv.z & 0xffff0000u), acc[5]);
        acc[6] = fmaf(w, __uint_as_float(hv.w << 16),         acc[6]);
        acc[7] = fmaf(w, __uint_as_float(hv.w & 0xffff0000u), acc[7]);
    }

    // reduce acc and sum across the 4 groups (lanes sharing cidx)
    #pragma unroll
    for (int c = 0; c < 8; ++c) {
        acc[c] += __shfl_xor(acc[c], 16);
        acc[c] += __shfl_xor(acc[c], 32);
    }
    sum += __shfl_xor(sum, 16);
    sum += __shfl_xor(sum, 32);

    if (g == 0) {
        float rs = 1.0f / (sum + 1e-16f);
        float4* ob = (float4*)(out + (size_t)wid * 128 + cidx * 8);
        ob[0] = make_float4(acc[0] * rs, acc[1] * rs, acc[2] * rs, acc[3] * rs);
        ob[1] = make_float4(acc[4] * rs, acc[5] * rs, acc[6] * rs, acc[7] * rs);
    }
}

// ---------------------------------------------------------------------------
extern "C" void kernel_launch(void* const* d_in, const int* in_sizes, int n_in,
                              void* d_out, int out_size, void* d_ws, size_t ws_size,
                              hipStream_t stream)
{
    const float* X  = (const float*)d_in[0];
    const int*   ei = (const int*)d_in[1];
    const float* W  = (const float*)d_in[2];
    const float* a  = (const float*)d_in[3];
    float* out = (float*)d_out;

    // workspace layout (4-byte elements), total ~34.4 MB
    unsigned short* h16 = (unsigned short*)d_ws;          // NN*128 bf16 = 6.4M elems
    float* asrc    = (float*)d_ws + 6400000;              // NN*4
    float* adst    = asrc + 400000;                       // NN*4
    int*   counts  = (int*)(adst + 400000);               // NN
    int*   cursor  = counts + 100000;                     // NN
    int*   csr_src = cursor + 100000;                     // NE
    int*   bsum    = csr_src + 1600000;                   // SCAN_BLK
    int*   boff    = bsum + 128;                          // SCAN_BLK

    hipMemsetAsync(counts, 0, NN * sizeof(int), stream);

    k1_gemm_alpha<<<(NN + 255) / 256, 256, 0, stream>>>(X, W, a, h16, asrc, adst);
    kc_count<<<(NE + 255) / 256, 256, 0, stream>>>(ei, counts);
    kscan1<<<SCAN_BLK, 1024, 0, stream>>>(counts, bsum);
    kscan2<<<1, 128, 0, stream>>>(bsum, boff);
    kscan3<<<SCAN_BLK, 1024, 0, stream>>>(counts, boff, cursor);
    k3_scatter<<<(NE + 255) / 256, 256, 0, stream>>>(ei, cursor, csr_src);
    k4_agg<<<(NN * 64 + 255) / 256, 256, 0, stream>>>(counts, cursor, csr_src,
                                                      asrc, adst, h16, out);
}

// Round 6
// 312.002 us; speedup vs baseline: 2.4816x; 1.1699x over previous
//
#include <hip/hip_runtime.h>

#define NN 100000
#define NE 1600000
#define SCAN_BLK 98   // ceil(100000/1024)

#define NXCD 8
#define RNG 12500                        // NN / NXCD: dst nodes per range
#define EPB 5120                         // edges per chunk
#define NCH ((NE + EPB - 1) / EPB)       // 313 chunks

static __device__ __forceinline__ unsigned f2bf(float f) {
    unsigned u = __float_as_uint(f);
    return (u + 0x7fffu + ((u >> 16) & 1u)) >> 16;   // RNE
}

// ---------------------------------------------------------------------------
// k1: h = X @ W  (fp32 compute, W in LDS, 4 rows x 32 cols per thread)
//     writes h as bf16 [NN][128]; fused per-node attention partial dots.
// ---------------------------------------------------------------------------
__global__ __launch_bounds__(256) void k1_gemm_alpha(
    const float* __restrict__ X, const float* __restrict__ W,
    const float* __restrict__ a, unsigned short* __restrict__ h16,
    float* __restrict__ asrc, float* __restrict__ adst)
{
    __shared__ float sW[128 * 128];  // 64 KB, swizzled
    {
        const float4* W4 = (const float4*)W;
        float4* sW4 = (float4*)sW;
        #pragma unroll
        for (int i = 0; i < 16; ++i) {
            int idx = threadIdx.x + i * 256;   // 0..4095 float4 granules
            int cg  = idx & 31;                // col granule within k-row
            int k   = idx >> 5;
            int cgs = cg ^ ((cg >> 3) & 3);    // bank swizzle (per col-quarter)
            sW4[(k << 5) + cgs] = W4[idx];
        }
    }
    __syncthreads();

    const int q  = threadIdx.x & 3;   // head / col-quarter (cols q*32..q*32+31)
    const int rg = threadIdx.x >> 2;  // 0..63
    const int row0 = blockIdx.x * 256;

    int rows[4];
    const float4* x4[4];
    #pragma unroll
    for (int i = 0; i < 4; ++i) {
        int r = row0 + rg + i * 64;
        rows[i] = r;
        int rc = r < NN ? r : (NN - 1);
        x4[i] = (const float4*)(X + (size_t)rc * 128);
    }

    float acc[4][32];
    #pragma unroll
    for (int i = 0; i < 4; ++i) {
        #pragma unroll
        for (int c = 0; c < 32; ++c) acc[i][c] = 0.f;
    }

    const float4* sW4r = (const float4*)sW;
    for (int k4 = 0; k4 < 32; ++k4) {
        float xs[4][4];
        #pragma unroll
        for (int i = 0; i < 4; ++i) {
            float4 xv = x4[i][k4];
            xs[i][0] = xv.x; xs[i][1] = xv.y; xs[i][2] = xv.z; xs[i][3] = xv.w;
        }
        #pragma unroll
        for (int j = 0; j < 4; ++j) {
            const int k = (k4 << 2) + j;
            const float4* wr = sW4r + (k << 5) + (q << 3);
            #pragma unroll
            for (int c = 0; c < 8; ++c) {
                float4 wv = wr[c ^ q];  // un-swizzle: logical granule c
                #pragma unroll
                for (int i = 0; i < 4; ++i) {
                    acc[i][(c << 2) + 0] = fmaf(xs[i][j], wv.x, acc[i][(c << 2) + 0]);
                    acc[i][(c << 2) + 1] = fmaf(xs[i][j], wv.y, acc[i][(c << 2) + 1]);
                    acc[i][(c << 2) + 2] = fmaf(xs[i][j], wv.z, acc[i][(c << 2) + 2]);
                    acc[i][(c << 2) + 3] = fmaf(xs[i][j], wv.w, acc[i][(c << 2) + 3]);
                }
            }
        }
    }

    // stage 'a' (256 floats) into LDS (reuse sW; all k-loop reads are done)
    __syncthreads();
    sW[threadIdx.x] = a[threadIdx.x];
    __syncthreads();
    const float* av = sW + q * 64;

    #pragma unroll
    for (int i = 0; i < 4; ++i) {
        if (rows[i] >= NN) continue;
        float ssrc = 0.f, sdst = 0.f;
        #pragma unroll
        for (int c = 0; c < 32; ++c) {
            ssrc = fmaf(acc[i][c], av[c], ssrc);
            sdst = fmaf(acc[i][c], av[32 + c], sdst);
        }
        // pack 32 accs -> 16 uints (bf16x2) -> 4 uint4 stores
        unsigned short* hr = h16 + (size_t)rows[i] * 128 + q * 32;
        uint4* hr4 = (uint4*)hr;
        #pragma unroll
        for (int g = 0; g < 4; ++g) {
            uint4 pk;
            pk.x = f2bf(acc[i][g * 8 + 0]) | (f2bf(acc[i][g * 8 + 1]) << 16);
            pk.y = f2bf(acc[i][g * 8 + 2]) | (f2bf(acc[i][g * 8 + 3]) << 16);
            pk.z = f2bf(acc[i][g * 8 + 4]) | (f2bf(acc[i][g * 8 + 5]) << 16);
            pk.w = f2bf(acc[i][g * 8 + 6]) | (f2bf(acc[i][g * 8 + 7]) << 16);
            hr4[g] = pk;
        }
        asrc[rows[i] * 4 + q] = ssrc;
        adst[rows[i] * 4 + q] = sdst;
    }
}

// ---------------------------------------------------------------------------
// kc: in-degree histogram, dst-range x chunk partitioned.
//     block (c = bid>>3, t = bid&7): sequential int4 read of dst-chunk c,
//     counts only dst in range t. With round-robin bid->XCD dispatch the
//     counter slice (50 KB) is XCD-local; correctness placement-independent.
// ---------------------------------------------------------------------------
__global__ __launch_bounds__(256) void kc_count(
    const int* __restrict__ ei, int* __restrict__ counts)
{
    const int c  = blockIdx.x >> 3;
    const int lo = (blockIdx.x & 7) * RNG;
    const int hi = lo + RNG;
    const int base = c * EPB;
    const int end  = min(NE, base + EPB);
    const int4* d4 = (const int4*)(ei + NE);
    for (int i = base + (threadIdx.x << 2); i < end; i += 1024) {
        int4 d = d4[i >> 2];
        if (d.x >= lo && d.x < hi) atomicAdd(counts + d.x, 1);
        if (d.y >= lo && d.y < hi) atomicAdd(counts + d.y, 1);
        if (d.z >= lo && d.z < hi) atomicAdd(counts + d.z, 1);
        if (d.w >= lo && d.w < hi) atomicAdd(counts + d.w, 1);
    }
}

// ---------------------------------------------------------------------------
// hierarchical exclusive scan of counts[NN] -> cursor[NN]
// ---------------------------------------------------------------------------
__global__ __launch_bounds__(1024) void kscan1(
    const int* __restrict__ counts, int* __restrict__ bsum)
{
    int i = blockIdx.x * 1024 + threadIdx.x;
    int v = (i < NN) ? counts[i] : 0;
    __shared__ int red[16];
    #pragma unroll
    for (int off = 1; off < 64; off <<= 1) v += __shfl_xor(v, off);
    if ((threadIdx.x & 63) == 0) red[threadIdx.x >> 6] = v;
    __syncthreads();
    if (threadIdx.x < 16) {
        int s = red[threadIdx.x];
        #pragma unroll
        for (int off = 1; off < 16; off <<= 1) s += __shfl_xor(s, off);
        if (threadIdx.x == 0) bsum[blockIdx.x] = s;
    }
}

__global__ __launch_bounds__(128) void kscan2(
    const int* __restrict__ bsum, int* __restrict__ boff)
{
    __shared__ int sh[128];
    int t = threadIdx.x;
    sh[t] = (t < SCAN_BLK) ? bsum[t] : 0;
    __syncthreads();
    for (int off = 1; off < 128; off <<= 1) {
        int u = (t >= off) ? sh[t - off] : 0;
        __syncthreads();
        sh[t] += u;
        __syncthreads();
    }
    if (t < SCAN_BLK) boff[t] = (t == 0) ? 0 : sh[t - 1];
}

__global__ __launch_bounds__(1024) void kscan3(
    const int* __restrict__ counts, const int* __restrict__ boff,
    int* __restrict__ cursor)
{
    __shared__ int sh[1024];
    int i = blockIdx.x * 1024 + threadIdx.x;
    int t = threadIdx.x;
    int v = (i < NN) ? counts[i] : 0;
    sh[t] = v;
    __syncthreads();
    for (int off = 1; off < 1024; off <<= 1) {
        int u = (t >= off) ? sh[t - off] : 0;
        __syncthreads();
        sh[t] += u;
        __syncthreads();
    }
    if (i < NN) cursor[i] = boff[blockIdx.x] + sh[t] - v;  // exclusive
}

// ---------------------------------------------------------------------------
// k3: CSR scatter, dst-range x chunk partitioned (same tiling as kc).
//     Range t's CSR slice is contiguous (~800 KB) -> L2-local dense writes.
//     after this kernel: cursor[n] = row_end(n); row_start(n) = cursor[n]-counts[n]
// ---------------------------------------------------------------------------
__global__ __launch_bounds__(256) void k3_scatter(
    const int* __restrict__ ei, int* __restrict__ cursor,
    int* __restrict__ csr_src)
{
    const int c  = blockIdx.x >> 3;
    const int lo = (blockIdx.x & 7) * RNG;
    const int hi = lo + RNG;
    const int base = c * EPB;
    const int end  = min(NE, base + EPB);
    const int4* s4 = (const int4*)ei;
    const int4* d4 = (const int4*)(ei + NE);
    for (int i = base + (threadIdx.x << 2); i < end; i += 1024) {
        int4 s = s4[i >> 2];
        int4 d = d4[i >> 2];
        if (d.x >= lo && d.x < hi) { int p = atomicAdd(cursor + d.x, 1); csr_src[p] = s.x; }
        if (d.y >= lo && d.y < hi) { int p = atomicAdd(cursor + d.y, 1); csr_src[p] = s.y; }
        if (d.z >= lo && d.z < hi) { int p = atomicAdd(cursor + d.z, 1); csr_src[p] = s.z; }
        if (d.w >= lo && d.w < hi) { int p = atomicAdd(cursor + d.w, 1); csr_src[p] = s.w; }
    }
}

// ---------------------------------------------------------------------------
// k4: one wave per dst node; four 16-lane groups each process every 4th edge.
//     Single pass: accumulate unnormalized sum_c(exp*h) AND scalar sum(exp);
//     normalize once at the end:  out = acc / (sum + eps).
// ---------------------------------------------------------------------------
__global__ __launch_bounds__(256) void k4_agg(
    const int* __restrict__ counts, const int* __restrict__ cursor,
    const int* __restrict__ csr_src, const float* __restrict__ asrc,
    const float* __restrict__ adst,
    const unsigned short* __restrict__ h16, float* __restrict__ out)
{
    int wid = (blockIdx.x * 256 + threadIdx.x) >> 6;
    if (wid >= NN) return;
    int l = threadIdx.x & 63;
    int g = l >> 4;           // edge subgroup 0..3
    int cidx = l & 15;        // col granule: cols cidx*8 .. cidx*8+7
    int head = cidx >> 2;

    int end = cursor[wid];
    int beg = end - counts[wid];

    float ad = adst[(size_t)wid * 4 + head];

    float acc[8];
    #pragma unroll
    for (int c = 0; c < 8; ++c) acc[c] = 0.f;
    float sum = 0.f;

    for (int i = beg + g; i < end; i += 4) {
        int src = csr_src[i];
        float sc = asrc[(size_t)src * 4 + head] + ad;
        sc = sc >= 0.f ? sc : 0.2f * sc;
        float w = __expf(sc);
        sum += w;
        uint4 hv = *(const uint4*)(h16 + (size_t)src * 128 + cidx * 8);
        acc[0] = fmaf(w, __uint_as_float(hv.x << 16),         acc[0]);
        acc[1] = fmaf(w, __uint_as_float(hv.x & 0xffff0000u), acc[1]);
        acc[2] = fmaf(w, __uint_as_float(hv.y << 16),         acc[2]);
        acc[3] = fmaf(w, __uint_as_float(hv.y & 0xffff0000u), acc[3]);
        acc[4] = fmaf(w, __uint_as_float(hv.z << 16),         acc[4]);
        acc[5] = fmaf(w, __uint_as_float(hv.z & 0xffff0000u), acc[5]);
        acc[6] = fmaf(w, __uint_as_float(hv.w << 16),         acc[6]);
        acc[7] = fmaf(w, __uint_as_float(hv.w & 0xffff0000u), acc[7]);
    }

    // reduce acc and sum across the 4 groups (lanes sharing cidx)
    #pragma unroll
    for (int c = 0; c < 8; ++c) {
        acc[c] += __shfl_xor(acc[c], 16);
        acc[c] += __shfl_xor(acc[c], 32);
    }
    sum += __shfl_xor(sum, 16);
    sum += __shfl_xor(sum, 32);

    if (g == 0) {
        float rs = 1.0f / (sum + 1e-16f);
        float4* ob = (float4*)(out + (size_t)wid * 128 + cidx * 8);
        ob[0] = make_float4(acc[0] * rs, acc[1] * rs, acc[2] * rs, acc[3] * rs);
        ob[1] = make_float4(acc[4] * rs, acc[5] * rs, acc[6] * rs, acc[7] * rs);
    }
}

// ---------------------------------------------------------------------------
extern "C" void kernel_launch(void* const* d_in, const int* in_sizes, int n_in,
                              void* d_out, int out_size, void* d_ws, size_t ws_size,
                              hipStream_t stream)
{
    const float* X  = (const float*)d_in[0];
    const int*   ei = (const int*)d_in[1];
    const float* W  = (const float*)d_in[2];
    const float* a  = (const float*)d_in[3];
    float* out = (float*)d_out;

    // workspace layout (4-byte elements), total ~34.4 MB
    unsigned short* h16 = (unsigned short*)d_ws;          // NN*128 bf16 = 6.4M elems
    float* asrc    = (float*)d_ws + 6400000;              // NN*4
    float* adst    = asrc + 400000;                       // NN*4
    int*   counts  = (int*)(adst + 400000);               // NN
    int*   cursor  = counts + 100000;                     // NN
    int*   csr_src = cursor + 100000;                     // NE
    int*   bsum    = csr_src + 1600000;                   // SCAN_BLK
    int*   boff    = bsum + 128;                          // SCAN_BLK

    hipMemsetAsync(counts, 0, NN * sizeof(int), stream);

    k1_gemm_alpha<<<(NN + 255) / 256, 256, 0, stream>>>(X, W, a, h16, asrc, adst);
    kc_count<<<NCH * NXCD, 256, 0, stream>>>(ei, counts);
    kscan1<<<SCAN_BLK, 1024, 0, stream>>>(counts, bsum);
    kscan2<<<1, 128, 0, stream>>>(bsum, boff);
    kscan3<<<SCAN_BLK, 1024, 0, stream>>>(counts, boff, cursor);
    k3_scatter<<<NCH * NXCD, 256, 0, stream>>>(ei, cursor, csr_src);
    k4_agg<<<(NN * 64 + 255) / 256, 256, 0, stream>>>(counts, cursor, csr_src,
                                                      asrc, adst, h16, out);
}

// Round 7
// 283.590 us; speedup vs baseline: 2.7302x; 1.1002x over previous
//
#include <hip/hip_runtime.h>

#define NN 100000
#define NE 1600000
#define SCAN_BLK 98   // ceil(100000/1024)

#define NXCD 8
#define RNG 12500                        // NN / NXCD: dst nodes per range
#define EPB 5120                         // edges per chunk
#define NCH ((NE + EPB - 1) / EPB)       // 313 chunks

typedef __attribute__((ext_vector_type(8))) __bf16 bf16x8;
typedef __attribute__((ext_vector_type(4))) float  f32x4;

static __device__ __forceinline__ unsigned f2bf(float f) {
    unsigned u = __float_as_uint(f);
    return (u + 0x7fffu + ((u >> 16) & 1u)) >> 16;   // RNE
}
static __device__ __forceinline__ float bf2f(unsigned b) {
    return __uint_as_float(b << 16);
}

union PkA { unsigned u[4]; bf16x8 b; };

// ---------------------------------------------------------------------------
// kwa: Wa[k, j] = sum_c W[k, q*32+c] * a[q, s*32+c],  q=j>>1, s=j&1.
//      (folds the per-node attention dots into the GEMM: alpha = X @ Wa)
// ---------------------------------------------------------------------------
__global__ __launch_bounds__(128) void kwa(
    const float* __restrict__ W, const float* __restrict__ a,
    float* __restrict__ Wa)
{
    int k = threadIdx.x;
    if (k >= 128) return;
    #pragma unroll
    for (int j = 0; j < 8; ++j) {
        int q = j >> 1, s = j & 1;
        float sum = 0.f;
        #pragma unroll
        for (int c = 0; c < 32; ++c)
            sum = fmaf(W[k * 128 + q * 32 + c], a[q * 64 + s * 32 + c], sum);
        Wa[k * 8 + j] = sum;
    }
}

// ---------------------------------------------------------------------------
// k1: [h | alpha] = X @ [W | Wa]  via bf16 MFMA, 2-pass split precision:
//     B = bf16_hi(B) + bf16_lo(B);  A = bf16(X) (residual ~6e-4, in budget).
//     Block = 256 thr = 4 waves; wave w owns rows blk*64+w*16..+16, all 9
//     N-tiles (144 cols: 0..127 h -> bf16 out, 128..135 alpha -> f32 out).
//     B staged in LDS in B-fragment order (1 ds_read_b128 per frag).
// ---------------------------------------------------------------------------
__global__ __launch_bounds__(256) void k1_gemm_alpha(
    const float* __restrict__ X, const float* __restrict__ W,
    const float* __restrict__ Wa, unsigned short* __restrict__ h16,
    float* __restrict__ asrc, float* __restrict__ adst)
{
    __shared__ unsigned short B0[9 * 4 * 64 * 8];   // 36 KB  hi
    __shared__ unsigned short B1[9 * 4 * 64 * 8];   // 36 KB  lo

    const int tid = threadIdx.x;

    // ---- stage B (fragment order): frag f=(tn,tk,l), elem j -> k=tk*32+8*(l>>4)+j,
    //      col = tn*16 + (l&15)
    #pragma unroll
    for (int it = 0; it < 9; ++it) {
        int f  = it * 256 + tid;       // 0..2303
        int l  = f & 63;
        int tk = (f >> 6) & 3;
        int tn = f >> 8;
        int col = tn * 16 + (l & 15);
        int kk  = tk * 32 + ((l >> 4) << 3);
        #pragma unroll
        for (int j = 0; j < 8; ++j) {
            float w;
            if (col < 128)       w = W[(size_t)(kk + j) * 128 + col];
            else if (col < 136)  w = Wa[(kk + j) * 8 + (col - 128)];
            else                 w = 0.f;
            unsigned hb = f2bf(w);
            unsigned lb = f2bf(w - bf2f(hb));
            B0[f * 8 + j] = (unsigned short)hb;
            B1[f * 8 + j] = (unsigned short)lb;
        }
    }
    __syncthreads();

    const int w = tid >> 6;
    const int l = tid & 63;
    const int rowbase = blockIdx.x * 64 + w * 16;
    const int row = rowbase + (l & 15);          // A m-index = lane%16
    const int rowc = row < NN ? row : (NN - 1);
    const float* xr = X + (size_t)rowc * 128 + ((l >> 4) << 3);

    f32x4 acc[9];
    #pragma unroll
    for (int t = 0; t < 9; ++t) acc[t] = (f32x4){0.f, 0.f, 0.f, 0.f};

    #pragma unroll
    for (int tk = 0; tk < 4; ++tk) {
        float4 xa = *(const float4*)(xr + tk * 32);
        float4 xb = *(const float4*)(xr + tk * 32 + 4);
        PkA pa;
        pa.u[0] = f2bf(xa.x) | (f2bf(xa.y) << 16);
        pa.u[1] = f2bf(xa.z) | (f2bf(xa.w) << 16);
        pa.u[2] = f2bf(xb.x) | (f2bf(xb.y) << 16);
        pa.u[3] = f2bf(xb.z) | (f2bf(xb.w) << 16);
        #pragma unroll
        for (int tn = 0; tn < 9; ++tn) {
            int off = (((tn << 2) + tk) * 64 + l) * 8;
            bf16x8 bh = *reinterpret_cast<const bf16x8*>(&B0[off]);
            bf16x8 bl = *reinterpret_cast<const bf16x8*>(&B1[off]);
            acc[tn] = __builtin_amdgcn_mfma_f32_16x16x32_bf16(pa.b, bh, acc[tn], 0, 0, 0);
            acc[tn] = __builtin_amdgcn_mfma_f32_16x16x32_bf16(pa.b, bl, acc[tn], 0, 0, 0);
        }
    }

    // ---- epilogue. C/D: col = l&15, local row = 4*(l>>4)+reg (guide-verified)
    __syncthreads();   // B reads done everywhere; reuse B0 as transpose scratch

    const int g = l >> 4;
    unsigned short* hs = B0 + w * 2048;     // wave-private 16x128 bf16 (4 KB)
    #pragma unroll
    for (int tn = 0; tn < 8; ++tn) {
        #pragma unroll
        for (int r = 0; r < 4; ++r)
            hs[((g << 2) + r) * 128 + (tn << 4) + (l & 15)] =
                (unsigned short)f2bf(acc[tn][r]);
    }
    // alpha tile (tn=8): cols 0..7 real -> j=(q,s)
    if ((l & 15) < 8) {
        int j = l & 15, q = j >> 1, s = j & 1;
        float* dp = s ? adst : asrc;
        #pragma unroll
        for (int r = 0; r < 4; ++r) {
            int rr = rowbase + (g << 2) + r;
            if (rr < NN) dp[rr * 4 + q] = acc[8][r];
        }
    }
    __syncthreads();

    // coalesced h16 store: wave's 16 rows are 4 KB contiguous (NN%16==0)
    if (rowbase < NN) {
        const uint4* sp = (const uint4*)hs;
        uint4* dp = (uint4*)(h16 + (size_t)rowbase * 128);
        #pragma unroll
        for (int i = 0; i < 4; ++i) dp[i * 64 + l] = sp[i * 64 + l];
    }
}

// ---------------------------------------------------------------------------
// kc: in-degree histogram, dst-range x chunk partitioned (XCD-local counters).
// ---------------------------------------------------------------------------
__global__ __launch_bounds__(256) void kc_count(
    const int* __restrict__ ei, int* __restrict__ counts)
{
    const int c  = blockIdx.x >> 3;
    const int lo = (blockIdx.x & 7) * RNG;
    const int hi = lo + RNG;
    const int base = c * EPB;
    const int end  = min(NE, base + EPB);
    const int4* d4 = (const int4*)(ei + NE);
    for (int i = base + (threadIdx.x << 2); i < end; i += 1024) {
        int4 d = d4[i >> 2];
        if (d.x >= lo && d.x < hi) atomicAdd(counts + d.x, 1);
        if (d.y >= lo && d.y < hi) atomicAdd(counts + d.y, 1);
        if (d.z >= lo && d.z < hi) atomicAdd(counts + d.z, 1);
        if (d.w >= lo && d.w < hi) atomicAdd(counts + d.w, 1);
    }
}

// ---------------------------------------------------------------------------
// hierarchical exclusive scan of counts[NN] -> cursor[NN]
// ---------------------------------------------------------------------------
__global__ __launch_bounds__(1024) void kscan1(
    const int* __restrict__ counts, int* __restrict__ bsum)
{
    int i = blockIdx.x * 1024 + threadIdx.x;
    int v = (i < NN) ? counts[i] : 0;
    __shared__ int red[16];
    #pragma unroll
    for (int off = 1; off < 64; off <<= 1) v += __shfl_xor(v, off);
    if ((threadIdx.x & 63) == 0) red[threadIdx.x >> 6] = v;
    __syncthreads();
    if (threadIdx.x < 16) {
        int s = red[threadIdx.x];
        #pragma unroll
        for (int off = 1; off < 16; off <<= 1) s += __shfl_xor(s, off);
        if (threadIdx.x == 0) bsum[blockIdx.x] = s;
    }
}

__global__ __launch_bounds__(128) void kscan2(
    const int* __restrict__ bsum, int* __restrict__ boff)
{
    __shared__ int sh[128];
    int t = threadIdx.x;
    sh[t] = (t < SCAN_BLK) ? bsum[t] : 0;
    __syncthreads();
    for (int off = 1; off < 128; off <<= 1) {
        int u = (t >= off) ? sh[t - off] : 0;
        __syncthreads();
        sh[t] += u;
        __syncthreads();
    }
    if (t < SCAN_BLK) boff[t] = (t == 0) ? 0 : sh[t - 1];
}

__global__ __launch_bounds__(1024) void kscan3(
    const int* __restrict__ counts, const int* __restrict__ boff,
    int* __restrict__ cursor)
{
    __shared__ int sh[1024];
    int i = blockIdx.x * 1024 + threadIdx.x;
    int t = threadIdx.x;
    int v = (i < NN) ? counts[i] : 0;
    sh[t] = v;
    __syncthreads();
    for (int off = 1; off < 1024; off <<= 1) {
        int u = (t >= off) ? sh[t - off] : 0;
        __syncthreads();
        sh[t] += u;
        __syncthreads();
    }
    if (i < NN) cursor[i] = boff[blockIdx.x] + sh[t] - v;  // exclusive
}

// ---------------------------------------------------------------------------
// k3: CSR scatter, dst-range x chunk partitioned (XCD-local CSR slice writes).
// ---------------------------------------------------------------------------
__global__ __launch_bounds__(256) void k3_scatter(
    const int* __restrict__ ei, int* __restrict__ cursor,
    int* __restrict__ csr_src)
{
    const int c  = blockIdx.x >> 3;
    const int lo = (blockIdx.x & 7) * RNG;
    const int hi = lo + RNG;
    const int base = c * EPB;
    const int end  = min(NE, base + EPB);
    const int4* s4 = (const int4*)ei;
    const int4* d4 = (const int4*)(ei + NE);
    for (int i = base + (threadIdx.x << 2); i < end; i += 1024) {
        int4 s = s4[i >> 2];
        int4 d = d4[i >> 2];
        if (d.x >= lo && d.x < hi) { int p = atomicAdd(cursor + d.x, 1); csr_src[p] = s.x; }
        if (d.y >= lo && d.y < hi) { int p = atomicAdd(cursor + d.y, 1); csr_src[p] = s.y; }
        if (d.z >= lo && d.z < hi) { int p = atomicAdd(cursor + d.z, 1); csr_src[p] = s.z; }
        if (d.w >= lo && d.w < hi) { int p = atomicAdd(cursor + d.w, 1); csr_src[p] = s.w; }
    }
}

// ---------------------------------------------------------------------------
// k4: one wave per dst node; four 16-lane groups each process every 4th edge.
//     Single pass: unnormalized sum(exp*h) and sum(exp); normalize at end.
// ---------------------------------------------------------------------------
__global__ __launch_bounds__(256) void k4_agg(
    const int* __restrict__ counts, const int* __restrict__ cursor,
    const int* __restrict__ csr_src, const float* __restrict__ asrc,
    const float* __restrict__ adst,
    const unsigned short* __restrict__ h16, float* __restrict__ out)
{
    int wid = (blockIdx.x * 256 + threadIdx.x) >> 6;
    if (wid >= NN) return;
    int l = threadIdx.x & 63;
    int g = l >> 4;           // edge subgroup 0..3
    int cidx = l & 15;        // col granule: cols cidx*8 .. cidx*8+7
    int head = cidx >> 2;

    int end = cursor[wid];
    int beg = end - counts[wid];

    float ad = adst[(size_t)wid * 4 + head];

    float acc[8];
    #pragma unroll
    for (int c = 0; c < 8; ++c) acc[c] = 0.f;
    float sum = 0.f;

    for (int i = beg + g; i < end; i += 4) {
        int src = csr_src[i];
        float sc = asrc[(size_t)src * 4 + head] + ad;
        sc = sc >= 0.f ? sc : 0.2f * sc;
        float w = __expf(sc);
        sum += w;
        uint4 hv = *(const uint4*)(h16 + (size_t)src * 128 + cidx * 8);
        acc[0] = fmaf(w, __uint_as_float(hv.x << 16),         acc[0]);
        acc[1] = fmaf(w, __uint_as_float(hv.x & 0xffff0000u), acc[1]);
        acc[2] = fmaf(w, __uint_as_float(hv.y << 16),         acc[2]);
        acc[3] = fmaf(w, __uint_as_float(hv.y & 0xffff0000u), acc[3]);
        acc[4] = fmaf(w, __uint_as_float(hv.z << 16),         acc[4]);
        acc[5] = fmaf(w, __uint_as_float(hv.z & 0xffff0000u), acc[5]);
        acc[6] = fmaf(w, __uint_as_float(hv.w << 16),         acc[6]);
        acc[7] = fmaf(w, __uint_as_float(hv.w & 0xffff0000u), acc[7]);
    }

    #pragma unroll
    for (int c = 0; c < 8; ++c) {
        acc[c] += __shfl_xor(acc[c], 16);
        acc[c] += __shfl_xor(acc[c], 32);
    }
    sum += __shfl_xor(sum, 16);
    sum += __shfl_xor(sum, 32);

    if (g == 0) {
        float rs = 1.0f / (sum + 1e-16f);
        float4* ob = (float4*)(out + (size_t)wid * 128 + cidx * 8);
        ob[0] = make_float4(acc[0] * rs, acc[1] * rs, acc[2] * rs, acc[3] * rs);
        ob[1] = make_float4(acc[4] * rs, acc[5] * rs, acc[6] * rs, acc[7] * rs);
    }
}

// ---------------------------------------------------------------------------
extern "C" void kernel_launch(void* const* d_in, const int* in_sizes, int n_in,
                              void* d_out, int out_size, void* d_ws, size_t ws_size,
                              hipStream_t stream)
{
    const float* X  = (const float*)d_in[0];
    const int*   ei = (const int*)d_in[1];
    const float* W  = (const float*)d_in[2];
    const float* a  = (const float*)d_in[3];
    float* out = (float*)d_out;

    // workspace layout (4-byte elements), total ~34.4 MB
    unsigned short* h16 = (unsigned short*)d_ws;          // NN*128 bf16 = 6.4M elems
    float* asrc    = (float*)d_ws + 6400000;              // NN*4
    float* adst    = asrc + 400000;                       // NN*4
    int*   counts  = (int*)(adst + 400000);               // NN
    int*   cursor  = counts + 100000;                     // NN
    int*   csr_src = cursor + 100000;                     // NE
    int*   bsum    = csr_src + 1600000;                   // SCAN_BLK
    int*   boff    = bsum + 128;                          // SCAN_BLK
    float* Wa      = (float*)(boff + 128);                // 128*8

    hipMemsetAsync(counts, 0, NN * sizeof(int), stream);

    kwa<<<1, 128, 0, stream>>>(W, a, Wa);
    k1_gemm_alpha<<<(NN + 63) / 64, 256, 0, stream>>>(X, W, Wa, h16, asrc, adst);
    kc_count<<<NCH * NXCD, 256, 0, stream>>>(ei, counts);
    kscan1<<<SCAN_BLK, 1024, 0, stream>>>(counts, bsum);
    kscan2<<<1, 128, 0, stream>>>(bsum, boff);
    kscan3<<<SCAN_BLK, 1024, 0, stream>>>(counts, boff, cursor);
    k3_scatter<<<NCH * NXCD, 256, 0, stream>>>(ei, cursor, csr_src);
    k4_agg<<<(NN * 64 + 255) / 256, 256, 0, stream>>>(counts, cursor, csr_src,
                                                      asrc, adst, h16, out);
}

// Round 8
// 277.612 us; speedup vs baseline: 2.7890x; 1.0215x over previous
//
#include <hip/hip_runtime.h>

#define NN 100000
#define NE 1600000
#define SCAN_BLK 98   // ceil(100000/1024)

#define NXCD 8
#define RNG 12500                        // NN / NXCD: dst nodes per range
#define EPB 5120                         // edges per chunk
#define NCH ((NE + EPB - 1) / EPB)       // 313 chunks

typedef __attribute__((ext_vector_type(8))) __bf16 bf16x8;
typedef __attribute__((ext_vector_type(4))) float  f32x4;

static __device__ __forceinline__ unsigned f2bf(float f) {
    unsigned u = __float_as_uint(f);
    return (u + 0x7fffu + ((u >> 16) & 1u)) >> 16;   // RNE
}
static __device__ __forceinline__ float bf2f(unsigned b) {
    return __uint_as_float(b << 16);
}

union PkA { unsigned u[4]; bf16x8 b; };

// ---------------------------------------------------------------------------
// kwa: Wa[k, j] = sum_c W[k, q*32+c] * a[q, s*32+c],  q=j>>1, s=j&1.
// ---------------------------------------------------------------------------
__global__ __launch_bounds__(128) void kwa(
    const float* __restrict__ W, const float* __restrict__ a,
    float* __restrict__ Wa)
{
    int k = threadIdx.x;
    if (k >= 128) return;
    #pragma unroll
    for (int j = 0; j < 8; ++j) {
        int q = j >> 1, s = j & 1;
        float sum = 0.f;
        #pragma unroll
        for (int c = 0; c < 32; ++c)
            sum = fmaf(W[k * 128 + q * 32 + c], a[q * 64 + s * 32 + c], sum);
        Wa[k * 8 + j] = sum;
    }
}

// ---------------------------------------------------------------------------
// k1: [h | alpha] = X @ [W | Wa]  via bf16 MFMA, 2-pass split precision.
// ---------------------------------------------------------------------------
__global__ __launch_bounds__(256) void k1_gemm_alpha(
    const float* __restrict__ X, const float* __restrict__ W,
    const float* __restrict__ Wa, unsigned short* __restrict__ h16,
    float* __restrict__ asrc, float* __restrict__ adst)
{
    __shared__ unsigned short B0[9 * 4 * 64 * 8];   // 36 KB  hi
    __shared__ unsigned short B1[9 * 4 * 64 * 8];   // 36 KB  lo

    const int tid = threadIdx.x;

    #pragma unroll
    for (int it = 0; it < 9; ++it) {
        int f  = it * 256 + tid;       // 0..2303
        int l  = f & 63;
        int tk = (f >> 6) & 3;
        int tn = f >> 8;
        int col = tn * 16 + (l & 15);
        int kk  = tk * 32 + ((l >> 4) << 3);
        #pragma unroll
        for (int j = 0; j < 8; ++j) {
            float w;
            if (col < 128)       w = W[(size_t)(kk + j) * 128 + col];
            else if (col < 136)  w = Wa[(kk + j) * 8 + (col - 128)];
            else                 w = 0.f;
            unsigned hb = f2bf(w);
            unsigned lb = f2bf(w - bf2f(hb));
            B0[f * 8 + j] = (unsigned short)hb;
            B1[f * 8 + j] = (unsigned short)lb;
        }
    }
    __syncthreads();

    const int w = tid >> 6;
    const int l = tid & 63;
    const int rowbase = blockIdx.x * 64 + w * 16;
    const int row = rowbase + (l & 15);          // A m-index = lane%16
    const int rowc = row < NN ? row : (NN - 1);
    const float* xr = X + (size_t)rowc * 128 + ((l >> 4) << 3);

    f32x4 acc[9];
    #pragma unroll
    for (int t = 0; t < 9; ++t) acc[t] = (f32x4){0.f, 0.f, 0.f, 0.f};

    #pragma unroll
    for (int tk = 0; tk < 4; ++tk) {
        float4 xa = *(const float4*)(xr + tk * 32);
        float4 xb = *(const float4*)(xr + tk * 32 + 4);
        PkA pa;
        pa.u[0] = f2bf(xa.x) | (f2bf(xa.y) << 16);
        pa.u[1] = f2bf(xa.z) | (f2bf(xa.w) << 16);
        pa.u[2] = f2bf(xb.x) | (f2bf(xb.y) << 16);
        pa.u[3] = f2bf(xb.z) | (f2bf(xb.w) << 16);
        #pragma unroll
        for (int tn = 0; tn < 9; ++tn) {
            int off = (((tn << 2) + tk) * 64 + l) * 8;
            bf16x8 bh = *reinterpret_cast<const bf16x8*>(&B0[off]);
            bf16x8 bl = *reinterpret_cast<const bf16x8*>(&B1[off]);
            acc[tn] = __builtin_amdgcn_mfma_f32_16x16x32_bf16(pa.b, bh, acc[tn], 0, 0, 0);
            acc[tn] = __builtin_amdgcn_mfma_f32_16x16x32_bf16(pa.b, bl, acc[tn], 0, 0, 0);
        }
    }

    __syncthreads();   // B reads done everywhere; reuse B0 as transpose scratch

    const int g = l >> 4;
    unsigned short* hs = B0 + w * 2048;     // wave-private 16x128 bf16 (4 KB)
    #pragma unroll
    for (int tn = 0; tn < 8; ++tn) {
        #pragma unroll
        for (int r = 0; r < 4; ++r)
            hs[((g << 2) + r) * 128 + (tn << 4) + (l & 15)] =
                (unsigned short)f2bf(acc[tn][r]);
    }
    if ((l & 15) < 8) {
        int j = l & 15, q = j >> 1, s = j & 1;
        float* dp = s ? adst : asrc;
        #pragma unroll
        for (int r = 0; r < 4; ++r) {
            int rr = rowbase + (g << 2) + r;
            if (rr < NN) dp[rr * 4 + q] = acc[8][r];
        }
    }
    __syncthreads();

    if (rowbase < NN) {
        const uint4* sp = (const uint4*)hs;
        uint4* dp = (uint4*)(h16 + (size_t)rowbase * 128);
        #pragma unroll
        for (int i = 0; i < 4; ++i) dp[i * 64 + l] = sp[i * 64 + l];
    }
}

// ---------------------------------------------------------------------------
// kc: in-degree histogram, dst-range x chunk partitioned (XCD-local counters).
// ---------------------------------------------------------------------------
__global__ __launch_bounds__(256) void kc_count(
    const int* __restrict__ ei, int* __restrict__ counts)
{
    const int c  = blockIdx.x >> 3;
    const int lo = (blockIdx.x & 7) * RNG;
    const int hi = lo + RNG;
    const int base = c * EPB;
    const int end  = min(NE, base + EPB);
    const int4* d4 = (const int4*)(ei + NE);
    for (int i = base + (threadIdx.x << 2); i < end; i += 1024) {
        int4 d = d4[i >> 2];
        if (d.x >= lo && d.x < hi) atomicAdd(counts + d.x, 1);
        if (d.y >= lo && d.y < hi) atomicAdd(counts + d.y, 1);
        if (d.z >= lo && d.z < hi) atomicAdd(counts + d.z, 1);
        if (d.w >= lo && d.w < hi) atomicAdd(counts + d.w, 1);
    }
}

// ---------------------------------------------------------------------------
// hierarchical exclusive scan of counts[NN] -> cursor[NN]
// ---------------------------------------------------------------------------
__global__ __launch_bounds__(1024) void kscan1(
    const int* __restrict__ counts, int* __restrict__ bsum)
{
    int i = blockIdx.x * 1024 + threadIdx.x;
    int v = (i < NN) ? counts[i] : 0;
    __shared__ int red[16];
    #pragma unroll
    for (int off = 1; off < 64; off <<= 1) v += __shfl_xor(v, off);
    if ((threadIdx.x & 63) == 0) red[threadIdx.x >> 6] = v;
    __syncthreads();
    if (threadIdx.x < 16) {
        int s = red[threadIdx.x];
        #pragma unroll
        for (int off = 1; off < 16; off <<= 1) s += __shfl_xor(s, off);
        if (threadIdx.x == 0) bsum[blockIdx.x] = s;
    }
}

__global__ __launch_bounds__(128) void kscan2(
    const int* __restrict__ bsum, int* __restrict__ boff)
{
    __shared__ int sh[128];
    int t = threadIdx.x;
    sh[t] = (t < SCAN_BLK) ? bsum[t] : 0;
    __syncthreads();
    for (int off = 1; off < 128; off <<= 1) {
        int u = (t >= off) ? sh[t - off] : 0;
        __syncthreads();
        sh[t] += u;
        __syncthreads();
    }
    if (t < SCAN_BLK) boff[t] = (t == 0) ? 0 : sh[t - 1];
}

__global__ __launch_bounds__(1024) void kscan3(
    const int* __restrict__ counts, const int* __restrict__ boff,
    int* __restrict__ cursor)
{
    __shared__ int sh[1024];
    int i = blockIdx.x * 1024 + threadIdx.x;
    int t = threadIdx.x;
    int v = (i < NN) ? counts[i] : 0;
    sh[t] = v;
    __syncthreads();
    for (int off = 1; off < 1024; off <<= 1) {
        int u = (t >= off) ? sh[t - off] : 0;
        __syncthreads();
        sh[t] += u;
        __syncthreads();
    }
    if (i < NN) cursor[i] = boff[blockIdx.x] + sh[t] - v;  // exclusive
}

// ---------------------------------------------------------------------------
// k3: CSR scatter, dst-range x chunk partitioned (XCD-local CSR slice writes).
// ---------------------------------------------------------------------------
__global__ __launch_bounds__(256) void k3_scatter(
    const int* __restrict__ ei, int* __restrict__ cursor,
    int* __restrict__ csr_src)
{
    const int c  = blockIdx.x >> 3;
    const int lo = (blockIdx.x & 7) * RNG;
    const int hi = lo + RNG;
    const int base = c * EPB;
    const int end  = min(NE, base + EPB);
    const int4* s4 = (const int4*)ei;
    const int4* d4 = (const int4*)(ei + NE);
    for (int i = base + (threadIdx.x << 2); i < end; i += 1024) {
        int4 s = s4[i >> 2];
        int4 d = d4[i >> 2];
        if (d.x >= lo && d.x < hi) { int p = atomicAdd(cursor + d.x, 1); csr_src[p] = s.x; }
        if (d.y >= lo && d.y < hi) { int p = atomicAdd(cursor + d.y, 1); csr_src[p] = s.y; }
        if (d.z >= lo && d.z < hi) { int p = atomicAdd(cursor + d.z, 1); csr_src[p] = s.z; }
        if (d.w >= lo && d.w < hi) { int p = atomicAdd(cursor + d.w, 1); csr_src[p] = s.w; }
    }
}

// ---------------------------------------------------------------------------
// k4: one wave per dst node; four 16-lane groups, each every 4th edge,
//     software-pipelined unroll-2: per iteration prefetch indices for the
//     NEXT pair (i+8, i+12) and issue BOTH current gathers (i, i+4) before
//     any use -> 2 h-row gathers in flight per group (8 per wave).
//     Invalid slots handled by weight-zeroing (clamped, speculation-safe).
// ---------------------------------------------------------------------------
__global__ __launch_bounds__(256) void k4_agg(
    const int* __restrict__ cursor, const int* __restrict__ csr_src,
    const float* __restrict__ asrc, const float* __restrict__ adst,
    const unsigned short* __restrict__ h16, float* __restrict__ out)
{
    int wid = (blockIdx.x * 256 + threadIdx.x) >> 6;
    if (wid >= NN) return;
    int l = threadIdx.x & 63;
    int g = l >> 4;           // edge subgroup 0..3
    int cidx = l & 15;        // col granule: cols cidx*8 .. cidx*8+7
    int head = cidx >> 2;

    int end = cursor[wid];
    int beg = wid ? cursor[wid - 1] : 0;

    float ad = adst[(size_t)wid * 4 + head];

    float acc[8];
    #pragma unroll
    for (int c = 0; c < 8; ++c) acc[c] = 0.f;
    float sum = 0.f;

    int i = beg + g;
    if (i < end) {
        const int last = end - 1;
        int sA = csr_src[i];
        int sB = csr_src[min(i + 4, last)];
        do {
            // prefetch next pair's indices (clamped; dup loads harmless)
            int i2 = i + 8;
            int sC = csr_src[min(i2, last)];
            int sD = csr_src[min(i2 + 4, last)];

            // issue both gathers before any use
            float aA = asrc[(size_t)sA * 4 + head];
            uint4 hA = *(const uint4*)(h16 + (size_t)sA * 128 + cidx * 8);
            float aB = asrc[(size_t)sB * 4 + head];
            uint4 hB = *(const uint4*)(h16 + (size_t)sB * 128 + cidx * 8);

            float scA = aA + ad; scA = scA >= 0.f ? scA : 0.2f * scA;
            float wA = __expf(scA);                       // i < end guaranteed
            float scB = aB + ad; scB = scB >= 0.f ? scB : 0.2f * scB;
            float wB = (i + 4 <= last) ? __expf(scB) : 0.f;
            sum += wA + wB;

            acc[0] = fmaf(wA, __uint_as_float(hA.x << 16),         acc[0]);
            acc[1] = fmaf(wA, __uint_as_float(hA.x & 0xffff0000u), acc[1]);
            acc[2] = fmaf(wA, __uint_as_float(hA.y << 16),         acc[2]);
            acc[3] = fmaf(wA, __uint_as_float(hA.y & 0xffff0000u), acc[3]);
            acc[4] = fmaf(wA, __uint_as_float(hA.z << 16),         acc[4]);
            acc[5] = fmaf(wA, __uint_as_float(hA.z & 0xffff0000u), acc[5]);
            acc[6] = fmaf(wA, __uint_as_float(hA.w << 16),         acc[6]);
            acc[7] = fmaf(wA, __uint_as_float(hA.w & 0xffff0000u), acc[7]);

            acc[0] = fmaf(wB, __uint_as_float(hB.x << 16),         acc[0]);
            acc[1] = fmaf(wB, __uint_as_float(hB.x & 0xffff0000u), acc[1]);
            acc[2] = fmaf(wB, __uint_as_float(hB.y << 16),         acc[2]);
            acc[3] = fmaf(wB, __uint_as_float(hB.y & 0xffff0000u), acc[3]);
            acc[4] = fmaf(wB, __uint_as_float(hB.z << 16),         acc[4]);
            acc[5] = fmaf(wB, __uint_as_float(hB.z & 0xffff0000u), acc[5]);
            acc[6] = fmaf(wB, __uint_as_float(hB.w << 16),         acc[6]);
            acc[7] = fmaf(wB, __uint_as_float(hB.w & 0xffff0000u), acc[7]);

            sA = sC; sB = sD; i = i2;
        } while (i < end);
    }

    // reduce acc and sum across the 4 groups (lanes sharing cidx)
    #pragma unroll
    for (int c = 0; c < 8; ++c) {
        acc[c] += __shfl_xor(acc[c], 16);
        acc[c] += __shfl_xor(acc[c], 32);
    }
    sum += __shfl_xor(sum, 16);
    sum += __shfl_xor(sum, 32);

    if (g == 0) {
        float rs = 1.0f / (sum + 1e-16f);
        float4* ob = (float4*)(out + (size_t)wid * 128 + cidx * 8);
        ob[0] = make_float4(acc[0] * rs, acc[1] * rs, acc[2] * rs, acc[3] * rs);
        ob[1] = make_float4(acc[4] * rs, acc[5] * rs, acc[6] * rs, acc[7] * rs);
    }
}

// ---------------------------------------------------------------------------
extern "C" void kernel_launch(void* const* d_in, const int* in_sizes, int n_in,
                              void* d_out, int out_size, void* d_ws, size_t ws_size,
                              hipStream_t stream)
{
    const float* X  = (const float*)d_in[0];
    const int*   ei = (const int*)d_in[1];
    const float* W  = (const float*)d_in[2];
    const float* a  = (const float*)d_in[3];
    float* out = (float*)d_out;

    // workspace layout (4-byte elements), total ~34.4 MB
    unsigned short* h16 = (unsigned short*)d_ws;          // NN*128 bf16 = 6.4M elems
    float* asrc    = (float*)d_ws + 6400000;              // NN*4
    float* adst    = asrc + 400000;                       // NN*4
    int*   counts  = (int*)(adst + 400000);               // NN
    int*   cursor  = counts + 100000;                     // NN
    int*   csr_src = cursor + 100000;                     // NE
    int*   bsum    = csr_src + 1600000;                   // SCAN_BLK
    int*   boff    = bsum + 128;                          // SCAN_BLK
    float* Wa      = (float*)(boff + 128);                // 128*8

    hipMemsetAsync(counts, 0, NN * sizeof(int), stream);

    kwa<<<1, 128, 0, stream>>>(W, a, Wa);
    k1_gemm_alpha<<<(NN + 63) / 64, 256, 0, stream>>>(X, W, Wa, h16, asrc, adst);
    kc_count<<<NCH * NXCD, 256, 0, stream>>>(ei, counts);
    kscan1<<<SCAN_BLK, 1024, 0, stream>>>(counts, bsum);
    kscan2<<<1, 128, 0, stream>>>(bsum, boff);
    kscan3<<<SCAN_BLK, 1024, 0, stream>>>(counts, boff, cursor);
    k3_scatter<<<NCH * NXCD, 256, 0, stream>>>(ei, cursor, csr_src);
    k4_agg<<<(NN * 64 + 255) / 256, 256, 0, stream>>>(cursor, csr_src,
                                                      asrc, adst, h16, out);
}